// Round 12
// baseline (476.324 us; speedup 1.0000x reference)
//
#include <hip/hip_runtime.h>

#define NN 384
#define RR 8
#define NR (NN * RR)   // 3072

typedef _Float16 half2v __attribute__((ext_vector_type(2)));
typedef _Float16 half8v __attribute__((ext_vector_type(8)));

struct h2x4 { half2v v[4]; };
static __device__ inline h2x4 split4(half8v h) { return __builtin_bit_cast(h2x4, h); }
static __device__ inline h2x4 split4i(int4 h) { return __builtin_bit_cast(h2x4, h); }

// ---------- prep: A (f32) -> A2h (f16) in ws; chunk q == A[8q..8q+8) ----------
__global__ void prep_a2(const float* __restrict__ A, _Float16* __restrict__ A2h) {
    const int q = blockIdx.x * 256 + threadIdx.x;     // 0..3071
    if (q < NN * RR) {
        const float4 f0 = reinterpret_cast<const float4*>(A)[2 * q];
        const float4 f1 = reinterpret_cast<const float4*>(A)[2 * q + 1];
        half8v h;
        h[0] = (_Float16)f0.x; h[1] = (_Float16)f0.y; h[2] = (_Float16)f0.z; h[3] = (_Float16)f0.w;
        h[4] = (_Float16)f1.x; h[5] = (_Float16)f1.y; h[6] = (_Float16)f1.z; h[7] = (_Float16)f1.w;
        reinterpret_cast<half8v*>(A2h)[q] = h;
    }
}

// ---------- build G for ALL pairs into ws: G[pair*64 + a*8 + b2] ----------
// thread -> (pair = bid*32 + t>>3, column a = t&7); math identical to r10's G phase.
__global__ __launch_bounds__(256)
void build_g(const float* __restrict__ Bf, const float* __restrict__ C,
             const int* __restrict__ x, _Float16* __restrict__ G)
{
    const int t = threadIdx.x;
    const long pair = (long)blockIdx.x * 32 + (t >> 3);
    const int a = t & 7;
    const int j = x[2 * pair];
    const int k = x[2 * pair + 1];
    const float* Bj = Bf + (size_t)j * RR;           // Bf[b2,j,c] at Bj[b2*NR + c]
    const float* Ck = C + (size_t)k * RR + a;        // C[c,k,a]   at Ck[c*NR]
    float ck[8];
    #pragma unroll
    for (int c = 0; c < 8; ++c)
        ck[c] = Ck[(size_t)c * NR];
    half8v h;
    #pragma unroll
    for (int b2 = 0; b2 < 8; ++b2) {
        const float4* br = reinterpret_cast<const float4*>(Bj + (size_t)b2 * NR);
        const float4 r0 = br[0];
        const float4 r1 = br[1];
        const float s = r0.x * ck[0] + r0.y * ck[1] + r0.z * ck[2] + r0.w * ck[3]
                      + r1.x * ck[4] + r1.y * ck[5] + r1.z * ck[6] + r1.w * ck[7];
        h[b2] = (_Float16)s;
    }
    *reinterpret_cast<half8v*>(G + pair * 64 + a * 8) = h;   // p = a*8 + b2
}

// ---------- main: 256 thr; block = 64 pairs x 192-i half; LDS = 24KB A2 half ----------
// g read from global G via wave-uniform (readfirstlane) address -> scalar loads;
// av per-lane from LDS; epilogue math identical to proven r10 path.
__global__ __launch_bounds__(256, 5)
void dtn_sg(const _Float16* __restrict__ A2h, const _Float16* __restrict__ G,
            float* __restrict__ out)
{
    __shared__ __align__(16) _Float16 A2c[8 * 192 * 8];   // 24576 B

    const int t = threadIdx.x;
    const long pb0 = (long)(blockIdx.x >> 1) * 64;        // first pair of block
    const int ih = blockIdx.x & 1;                        // i-half: [0,192) or [192,384)

    // ---- Stage this i-half of A2: 1536 chunks, 6 iters (f16 direct, no cvt).
    #pragma unroll
    for (int it = 0; it < 6; ++it) {
        const int L = it * 256 + t;                       // 0..1535
        const int c = L / 192;
        const int il = L - c * 192;
        reinterpret_cast<int4*>(A2c)[L] =
            reinterpret_cast<const int4*>(A2h)[c * NN + ih * 192 + il];
    }
    __syncthreads();

    const int lane = t & 63;
    const int wvu = __builtin_amdgcn_readfirstlane(t >> 6);   // uniform wave id
    // Wave owns pairs pb0 + wvu*16 .. +15. G rows for them: uniform base.
    const int4* gw = reinterpret_cast<const int4*>(G + (size_t)(pb0 + wvu * 16) * 64);

    float acc[16][3];
    #pragma unroll
    for (int pp = 0; pp < 16; ++pp)
        #pragma unroll
        for (int ii = 0; ii < 3; ++ii)
            acc[pp][ii] = 0.f;

    #pragma unroll 1
    for (int c = 0; c < 8; ++c) {
        h2x4 av[3];
        #pragma unroll
        for (int ii = 0; ii < 3; ++ii)
            av[ii] = split4(*reinterpret_cast<const half8v*>(
                &A2c[(size_t)(c * 192 + lane + 64 * ii) * 8]));
        #pragma unroll
        for (int pp = 0; pp < 16; ++pp) {
            const h2x4 g = split4i(gw[pp * 8 + c]);       // uniform 16B -> s_load
            #pragma unroll
            for (int ii = 0; ii < 3; ++ii) {
                float s = acc[pp][ii];
                s = __builtin_amdgcn_fdot2(g.v[0], av[ii].v[0], s, false);
                s = __builtin_amdgcn_fdot2(g.v[1], av[ii].v[1], s, false);
                s = __builtin_amdgcn_fdot2(g.v[2], av[ii].v[2], s, false);
                s = __builtin_amdgcn_fdot2(g.v[3], av[ii].v[3], s, false);
                acc[pp][ii] = s;
            }
        }
    }

    // ---- Store: per (pp,ii) the wave's 64 lanes write 256B contiguous.
    float* obase = out + (size_t)(pb0 + wvu * 16) * NN + ih * 192 + lane;
    #pragma unroll
    for (int pp = 0; pp < 16; ++pp) {
        #pragma unroll
        for (int ii = 0; ii < 3; ++ii)
            obase[(size_t)pp * NN + ii * 64] = acc[pp][ii];
    }
}

// ---------- fallback (r10 kernel, 266us) if ws too small ----------
__global__ __launch_bounds__(512, 4)
void dtn_dot2d(const float* __restrict__ A, const float* __restrict__ Bf,
               const float* __restrict__ C, const int* __restrict__ x,
               float* __restrict__ out)
{
    __shared__ __align__(16) _Float16 A2c[8 * NN * 8];
    __shared__ __align__(16) _Float16 Gh[256 * 64];
    const int t = threadIdx.x;
    const long b0 = (long)blockIdx.x * 256;
    #pragma unroll
    for (int it = 0; it < 6; ++it) {
        const int idx = t + it * 512;
        const int i = idx >> 3;
        const int a = idx & 7;
        const float4* src = reinterpret_cast<const float4*>(A + (size_t)a * NR + (size_t)i * RR);
        const float4 f0 = src[0];
        const float4 f1 = src[1];
        half8v h;
        h[0] = (_Float16)f0.x; h[1] = (_Float16)f0.y; h[2] = (_Float16)f0.z; h[3] = (_Float16)f0.w;
        h[4] = (_Float16)f1.x; h[5] = (_Float16)f1.y; h[6] = (_Float16)f1.z; h[7] = (_Float16)f1.w;
        *reinterpret_cast<half8v*>(&A2c[(size_t)(a * NN + i) * 8]) = h;
    }
    #pragma unroll 1
    for (int bt = 0; bt < 4; ++bt) {
        const int bl = bt * 64 + (t >> 3);
        const int a  = t & 7;
        const int j = x[2 * (b0 + bl)];
        const int k = x[2 * (b0 + bl) + 1];
        const float* Bj = Bf + (size_t)j * RR;
        const float* Ck = C + (size_t)k * RR + a;
        float ck[8];
        #pragma unroll
        for (int c = 0; c < 8; ++c) ck[c] = Ck[(size_t)c * NR];
        half8v h;
        #pragma unroll
        for (int b2 = 0; b2 < 8; ++b2) {
            const float4* br = reinterpret_cast<const float4*>(Bj + (size_t)b2 * NR);
            const float4 r0 = br[0];
            const float4 r1 = br[1];
            const float s = r0.x * ck[0] + r0.y * ck[1] + r0.z * ck[2] + r0.w * ck[3]
                          + r1.x * ck[4] + r1.y * ck[5] + r1.z * ck[6] + r1.w * ck[7];
            h[b2] = (_Float16)s;
        }
        *reinterpret_cast<half8v*>(&Gh[bl * 64 + a * 8]) = h;
    }
    __syncthreads();
    const int lane = t & 63;
    const int wv = t >> 6;
    #pragma unroll 1
    for (int bt = 0; bt < 4; ++bt) {
        float acc[8][6];
        #pragma unroll
        for (int pp = 0; pp < 8; ++pp)
            #pragma unroll
            for (int ii = 0; ii < 6; ++ii) acc[pp][ii] = 0.f;
        #pragma unroll 1
        for (int c = 0; c < 8; ++c) {
            h2x4 av[6];
            #pragma unroll
            for (int ii = 0; ii < 6; ++ii)
                av[ii] = split4(*reinterpret_cast<const half8v*>(&A2c[(size_t)(c * NN + lane + 64 * ii) * 8]));
            #pragma unroll
            for (int pp = 0; pp < 8; ++pp) {
                const h2x4 g = split4(*reinterpret_cast<const half8v*>(&Gh[(bt * 64 + wv * 8 + pp) * 64 + c * 8]));
                #pragma unroll
                for (int ii = 0; ii < 6; ++ii) {
                    float s = acc[pp][ii];
                    s = __builtin_amdgcn_fdot2(g.v[0], av[ii].v[0], s, false);
                    s = __builtin_amdgcn_fdot2(g.v[1], av[ii].v[1], s, false);
                    s = __builtin_amdgcn_fdot2(g.v[2], av[ii].v[2], s, false);
                    s = __builtin_amdgcn_fdot2(g.v[3], av[ii].v[3], s, false);
                    acc[pp][ii] = s;
                }
            }
        }
        float* obase = out + (size_t)(b0 + bt * 64 + wv * 8) * NN + lane;
        #pragma unroll
        for (int pp = 0; pp < 8; ++pp)
            #pragma unroll
            for (int ii = 0; ii < 6; ++ii)
                obase[(size_t)pp * NN + ii * 64] = acc[pp][ii];
    }
}

extern "C" void kernel_launch(void* const* d_in, const int* in_sizes, int n_in,
                              void* d_out, int out_size, void* d_ws, size_t ws_size,
                              hipStream_t stream) {
    const float* A  = (const float*)d_in[0];
    const float* Bf = (const float*)d_in[1];
    const float* C  = (const float*)d_in[2];
    const int*   x  = (const int*)d_in[3];
    float* out = (float*)d_out;
    const int B = in_sizes[3] / 2;           // 524288
    const size_t gOff = 65536;               // G at 64KB offset (A2h in first 48KB)
    const size_t need = gOff + (size_t)B * 64 * sizeof(_Float16);
    if (ws_size >= need) {
        _Float16* A2h = (_Float16*)d_ws;
        _Float16* G   = (_Float16*)((char*)d_ws + gOff);
        prep_a2<<<12, 256, 0, stream>>>(A, A2h);
        build_g<<<B / 32, 256, 0, stream>>>(Bf, C, x, G);
        dtn_sg<<<(B / 64) * 2, 256, 0, stream>>>(A2h, G, out);
    } else {
        dtn_dot2d<<<B / 256, 512, 0, stream>>>(A, Bf, C, x, out);
    }
}

// Round 13
// 179.828 us; speedup vs baseline: 2.6488x; 2.6488x over previous
//
#include <hip/hip_runtime.h>

#define NN 384
#define RR 8
#define NR (NN * RR)   // 3072
#define IPAD 385       // padded i-stride for A2c (breaks c-dimension bank aliasing)
#define GSTR 72        // Gh row stride in f16 (144B rows -> bank spread)

typedef _Float16 half4v __attribute__((ext_vector_type(4)));
typedef _Float16 half8v __attribute__((ext_vector_type(8)));
typedef float f32x4 __attribute__((ext_vector_type(4)));

// out[b,i] = sum_{a,b2,c} A[a,i,b2]*Bf[b2,j_b,c]*C[c,k_b,a]
// G[b2,a] = sum_c Bf[b2,j,c]*C[c,k,a];  out[b,i] = sum_p A2[i,p]*G[p], p=a*8+b2.
// r13: r10's proven staging + G phases, epilogue replaced by v_mfma_f32_16x16x16_f16
// tiles using the CLASSIC (CDNA1/2/3 lab-notes) fragment maps:
//   A: lane l -> row l%16,       k = 4*(l/16)+e (e=0..3 contiguous)
//   B: lane l -> col l%16,       k = 4*(l/16)+e
//   D: lane l -> row 4*(l/16)+r, col l%16   (== m89 HW-verified D map)
__global__ __launch_bounds__(512, 4)
void dtn_mfma16(const float* __restrict__ A, const float* __restrict__ Bf,
                const float* __restrict__ C, const int* __restrict__ x,
                float* __restrict__ out)
{
    __shared__ __align__(16) _Float16 A2c[8 * IPAD * 8];   // 49280 B
    __shared__ __align__(16) _Float16 Gh[64 * GSTR];       //  9216 B  (58.5 KB total)

    const int t = threadIdx.x;
    const long b0 = (long)blockIdx.x * 256;

    // ---- Stage A2c[(a*IPAD+i)*8+e] = f16(A[a*NR + i*8 + e]); 3072 chunks, 6 iters.
    #pragma unroll
    for (int it = 0; it < 6; ++it) {
        const int idx = t + it * 512;     // 0..3071
        const int i = idx >> 3;
        const int a = idx & 7;
        const float4* src = reinterpret_cast<const float4*>(A + (size_t)a * NR + (size_t)i * RR);
        const float4 f0 = src[0];
        const float4 f1 = src[1];
        half8v h;
        h[0] = (_Float16)f0.x; h[1] = (_Float16)f0.y; h[2] = (_Float16)f0.z; h[3] = (_Float16)f0.w;
        h[4] = (_Float16)f1.x; h[5] = (_Float16)f1.y; h[6] = (_Float16)f1.z; h[7] = (_Float16)f1.w;
        *reinterpret_cast<half8v*>(&A2c[(size_t)(a * IPAD + i) * 8]) = h;
    }

    const int lane = t & 63;
    const int w    = t >> 6;     // wave 0..7
    const int mt   = w & 3;      // M-tile (16 pairs) within the 64-pair batch
    const int nh   = w >> 2;     // i-half: [0,192) or [192,384)
    const int a16  = lane & 15;
    const int q    = lane >> 4;  // 0..3

    #pragma unroll 1
    for (int bt = 0; bt < 4; ++bt) {
        __syncthreads();   // Gh free to overwrite (also covers staging on bt=0)

        // ---- G phase (math identical to proven r10): thread -> (pair bl=t>>3, col a=t&7)
        {
            const int bl = t >> 3;
            const int a  = t & 7;
            const long pair = b0 + bt * 64 + bl;
            const int j = x[2 * pair];
            const int k = x[2 * pair + 1];
            const float* Bj = Bf + (size_t)j * RR;       // Bf[b2,j,c] at Bj[b2*NR + c]
            const float* Ck = C + (size_t)k * RR + a;    // C[c,k,a]   at Ck[c*NR]
            float ck[8];
            #pragma unroll
            for (int c = 0; c < 8; ++c)
                ck[c] = Ck[(size_t)c * NR];
            half8v h;
            #pragma unroll
            for (int b2 = 0; b2 < 8; ++b2) {
                const float4* br = reinterpret_cast<const float4*>(Bj + (size_t)b2 * NR);
                const float4 r0 = br[0];
                const float4 r1 = br[1];
                const float s = r0.x * ck[0] + r0.y * ck[1] + r0.z * ck[2] + r0.w * ck[3]
                              + r1.x * ck[4] + r1.y * ck[5] + r1.z * ck[6] + r1.w * ck[7];
                h[b2] = (_Float16)s;
            }
            *reinterpret_cast<half8v*>(&Gh[bl * GSTR + a * 8]) = h;   // p = a*8 + b2
        }
        __syncthreads();

        // ---- A-fragments for this wave's M-tile: row = mt*16+a16, k-window kt*16.
        const half4v af0 = *reinterpret_cast<const half4v*>(&Gh[(mt * 16 + a16) * GSTR +  0 + 4 * q]);
        const half4v af1 = *reinterpret_cast<const half4v*>(&Gh[(mt * 16 + a16) * GSTR + 16 + 4 * q]);
        const half4v af2 = *reinterpret_cast<const half4v*>(&Gh[(mt * 16 + a16) * GSTR + 32 + 4 * q]);
        const half4v af3 = *reinterpret_cast<const half4v*>(&Gh[(mt * 16 + a16) * GSTR + 48 + 4 * q]);

        const long prow0 = b0 + bt * 64 + mt * 16 + 4 * q;   // D row base for this lane

        // ---- 12 N-tiles of 16 i each; B-frag: A2[n0+a16][k=16kt+4q+e]
        //      p = 16kt+4q+e -> chunk c = 2kt+(q>>1), elem = 4*(q&1)+e.
        #pragma unroll 2
        for (int nt = 0; nt < 12; ++nt) {
            const int n0 = nh * 192 + nt * 16;
            const int col = n0 + a16;
            f32x4 acc = {0.f, 0.f, 0.f, 0.f};
            const half4v bf0 = *reinterpret_cast<const half4v*>(
                &A2c[(size_t)((0 + (q >> 1)) * IPAD + col) * 8 + 4 * (q & 1)]);
            acc = __builtin_amdgcn_mfma_f32_16x16x16f16(af0, bf0, acc, 0, 0, 0);
            const half4v bf1 = *reinterpret_cast<const half4v*>(
                &A2c[(size_t)((2 + (q >> 1)) * IPAD + col) * 8 + 4 * (q & 1)]);
            acc = __builtin_amdgcn_mfma_f32_16x16x16f16(af1, bf1, acc, 0, 0, 0);
            const half4v bf2 = *reinterpret_cast<const half4v*>(
                &A2c[(size_t)((4 + (q >> 1)) * IPAD + col) * 8 + 4 * (q & 1)]);
            acc = __builtin_amdgcn_mfma_f32_16x16x16f16(af2, bf2, acc, 0, 0, 0);
            const half4v bf3 = *reinterpret_cast<const half4v*>(
                &A2c[(size_t)((6 + (q >> 1)) * IPAD + col) * 8 + 4 * (q & 1)]);
            acc = __builtin_amdgcn_mfma_f32_16x16x16f16(af3, bf3, acc, 0, 0, 0);

            float* op = out + (size_t)prow0 * NN + col;
            op[0]            = acc[0];
            op[(size_t)NN]   = acc[1];
            op[(size_t)2*NN] = acc[2];
            op[(size_t)3*NN] = acc[3];
        }
    }
}

extern "C" void kernel_launch(void* const* d_in, const int* in_sizes, int n_in,
                              void* d_out, int out_size, void* d_ws, size_t ws_size,
                              hipStream_t stream) {
    const float* A  = (const float*)d_in[0];
    const float* Bf = (const float*)d_in[1];
    const float* C  = (const float*)d_in[2];
    const int*   x  = (const int*)d_in[3];
    float* out = (float*)d_out;
    const int B = in_sizes[3] / 2;           // 524288
    dtn_mfma16<<<B / 256, 512, 0, stream>>>(A, Bf, C, x, out);
}